// Round 1
// baseline (1019.808 us; speedup 1.0000x reference)
//
#include <hip/hip_runtime.h>
#include <stdint.h>

#define NN 50000
#define EE 1600000
#define IN_DIMC 256
#define HIDC 128
#define EPSC 1e-5f

// ---------------------------------------------------------------------------
// GEMM: C[M,128] = A1@W1 (+ A2@W2) + bias.  A row-major [M,K], W row-major
// [K,128]. Tile 64 rows x 128 cols, Kc=64, 256 threads, 4x8 micro-tile.
// ---------------------------------------------------------------------------
__global__ __launch_bounds__(256) void gemm_kernel(
    const float* __restrict__ A1, const float* __restrict__ W1, int K1,
    const float* __restrict__ A2, const float* __restrict__ W2, int K2,
    const float* __restrict__ bias, float* __restrict__ C, int M)
{
    __shared__ float As[64][68];   // pad 68: 2-way-only conflict on reads (free)
    __shared__ float Bs[64][132];  // pad 132: keeps 16B alignment for float4

    const int t  = threadIdx.x;
    const int tr = t >> 4;   // 0..15 -> rows tr*4 .. tr*4+3
    const int tc = t & 15;   // 0..15 -> cols tc*8 .. tc*8+7
    const int row0 = blockIdx.x * 64;

    float acc[4][8];
    #pragma unroll
    for (int i = 0; i < 4; i++)
        #pragma unroll
        for (int j = 0; j < 8; j++) acc[i][j] = 0.0f;

    for (int s = 0; s < 2; s++) {
        const float* A = s ? A2 : A1;
        const float* W = s ? W2 : W1;
        const int    K = s ? K2 : K1;
        if (A == nullptr) continue;

        for (int kc = 0; kc < K; kc += 64) {
            // load A tile: 64 rows x 64 cols (16 float4 per row)
            {
                const int lr  = t >> 4;   // 0..15
                const int lc4 = t & 15;   // 0..15
                #pragma unroll
                for (int p = 0; p < 4; p++) {
                    const int r  = lr + p * 16;
                    int gr = row0 + r;
                    if (gr > M - 1) gr = M - 1;  // clamp; bogus rows never stored
                    const float4 v = *(const float4*)(A + (size_t)gr * K + kc + lc4 * 4);
                    *(float4*)&As[r][lc4 * 4] = v;
                }
            }
            // load W tile: 64 k x 128 cols (32 float4 per k-row)
            {
                const int lk  = t >> 5;   // 0..7
                const int wc4 = t & 31;   // 0..31
                #pragma unroll
                for (int p = 0; p < 8; p++) {
                    const int k = lk + p * 8;
                    const float4 v = *(const float4*)(W + (size_t)(kc + k) * HIDC + wc4 * 4);
                    *(float4*)&Bs[k][wc4 * 4] = v;
                }
            }
            __syncthreads();

            #pragma unroll 4
            for (int k = 0; k < 64; k++) {
                const float a0 = As[tr * 4 + 0][k];
                const float a1 = As[tr * 4 + 1][k];
                const float a2 = As[tr * 4 + 2][k];
                const float a3 = As[tr * 4 + 3][k];
                const float4 b0 = *(const float4*)&Bs[k][tc * 8];
                const float4 b1 = *(const float4*)&Bs[k][tc * 8 + 4];
                acc[0][0] += a0 * b0.x; acc[0][1] += a0 * b0.y; acc[0][2] += a0 * b0.z; acc[0][3] += a0 * b0.w;
                acc[0][4] += a0 * b1.x; acc[0][5] += a0 * b1.y; acc[0][6] += a0 * b1.z; acc[0][7] += a0 * b1.w;
                acc[1][0] += a1 * b0.x; acc[1][1] += a1 * b0.y; acc[1][2] += a1 * b0.z; acc[1][3] += a1 * b0.w;
                acc[1][4] += a1 * b1.x; acc[1][5] += a1 * b1.y; acc[1][6] += a1 * b1.z; acc[1][7] += a1 * b1.w;
                acc[2][0] += a2 * b0.x; acc[2][1] += a2 * b0.y; acc[2][2] += a2 * b0.z; acc[2][3] += a2 * b0.w;
                acc[2][4] += a2 * b1.x; acc[2][5] += a2 * b1.y; acc[2][6] += a2 * b1.z; acc[2][7] += a2 * b1.w;
                acc[3][0] += a3 * b0.x; acc[3][1] += a3 * b0.y; acc[3][2] += a3 * b0.z; acc[3][3] += a3 * b0.w;
                acc[3][4] += a3 * b1.x; acc[3][5] += a3 * b1.y; acc[3][6] += a3 * b1.z; acc[3][7] += a3 * b1.w;
            }
            __syncthreads();
        }
    }

    const float4 bv0 = *(const float4*)(bias + tc * 8);
    const float4 bv1 = *(const float4*)(bias + tc * 8 + 4);
    #pragma unroll
    for (int i = 0; i < 4; i++) {
        const int gr = row0 + tr * 4 + i;
        if (gr < M) {
            float4 o0, o1;
            o0.x = acc[i][0] + bv0.x; o0.y = acc[i][1] + bv0.y;
            o0.z = acc[i][2] + bv0.z; o0.w = acc[i][3] + bv0.w;
            o1.x = acc[i][4] + bv1.x; o1.y = acc[i][5] + bv1.y;
            o1.z = acc[i][6] + bv1.z; o1.w = acc[i][7] + bv1.w;
            *(float4*)(C + (size_t)gr * HIDC + tc * 8)     = o0;
            *(float4*)(C + (size_t)gr * HIDC + tc * 8 + 4) = o1;
        }
    }
}

// ---------------------------------------------------------------------------
// Column stats: stats[0..127]=sum, stats[128..255]=sumsq (atomic partials).
// ---------------------------------------------------------------------------
__global__ __launch_bounds__(256) void colstats_kernel(
    const float* __restrict__ T, float* __restrict__ stats, int M)
{
    const int t = threadIdx.x;
    const int col = t & 127;
    const int half = t >> 7;
    const int rowsPerBlock = (M + gridDim.x - 1) / gridDim.x;
    const int r0 = blockIdx.x * rowsPerBlock;
    int r1 = r0 + rowsPerBlock; if (r1 > M) r1 = M;

    float s = 0.0f, q = 0.0f;
    for (int r = r0 + half; r < r1; r += 2) {
        const float v = T[(size_t)r * HIDC + col];
        s += v; q += v * v;
    }
    __shared__ float ls[256], lq[256];
    ls[t] = s; lq[t] = q;
    __syncthreads();
    if (t < 128) {
        atomicAdd(&stats[t],        ls[t] + ls[t + 128]);
        atomicAdd(&stats[128 + t],  lq[t] + lq[t + 128]);
    }
}

// ---------------------------------------------------------------------------
// BN apply (+ optional relu): dst = (src - mean) * g / sqrt(var+eps) + beta
// ---------------------------------------------------------------------------
__global__ __launch_bounds__(256) void bn_apply_kernel(
    const float* __restrict__ src, float* __restrict__ dst,
    const float* __restrict__ stats, const float* __restrict__ gamma,
    const float* __restrict__ beta, int relu, int M)
{
    __shared__ float sc[128], sh[128];
    const int t = threadIdx.x;
    if (t < 128) {
        const float invM = 1.0f / (float)M;
        const float mean = stats[t] * invM;
        float var = stats[128 + t] * invM - mean * mean;
        if (var < 0.0f) var = 0.0f;
        const float s = gamma[t] / sqrtf(var + EPSC);
        sc[t] = s;
        sh[t] = beta[t] - mean * s;
    }
    __syncthreads();

    const int total4 = M * HIDC / 4;
    for (int i = blockIdx.x * 256 + t; i < total4; i += gridDim.x * 256) {
        float4 v = ((const float4*)src)[i];
        const int c = (i * 4) & 127;
        v.x = v.x * sc[c]     + sh[c];
        v.y = v.y * sc[c + 1] + sh[c + 1];
        v.z = v.z * sc[c + 2] + sh[c + 2];
        v.w = v.w * sc[c + 3] + sh[c + 3];
        if (relu) {
            v.x = fmaxf(v.x, 0.0f); v.y = fmaxf(v.y, 0.0f);
            v.z = fmaxf(v.z, 0.0f); v.w = fmaxf(v.w, 0.0f);
        }
        ((float4*)dst)[i] = v;
    }
}

// ---------------------------------------------------------------------------
// CSR build: histogram -> scan -> fill
// ---------------------------------------------------------------------------
__global__ void hist_kernel(const int* __restrict__ dstArr, int* __restrict__ deg)
{
    for (int e = blockIdx.x * blockDim.x + threadIdx.x; e < EE;
         e += gridDim.x * blockDim.x)
        atomicAdd(&deg[dstArr[e]], 1);
}

__global__ __launch_bounds__(256) void scan_kernel(
    const int* __restrict__ deg, int* __restrict__ row_ptr, int* __restrict__ cursor)
{
    __shared__ int wtot[4];
    const int t = threadIdx.x;
    const int lane = t & 63, w = t >> 6;
    int carry = 0;
    for (int base = 0; base < NN; base += 256) {
        const int i = base + t;
        const int v = (i < NN) ? deg[i] : 0;
        int x = v;
        #pragma unroll
        for (int off = 1; off < 64; off <<= 1) {
            const int y = __shfl_up(x, off);
            if (lane >= off) x += y;
        }
        if (lane == 63) wtot[w] = x;
        __syncthreads();
        int woff = 0;
        #pragma unroll
        for (int j = 0; j < 4; j++) if (j < w) woff += wtot[j];
        if (i < NN) {
            const int ex = carry + woff + x - v;
            row_ptr[i] = ex;
            cursor[i]  = ex;
        }
        carry += wtot[0] + wtot[1] + wtot[2] + wtot[3];
        __syncthreads();
    }
    if (t == 0) row_ptr[NN] = carry;
}

__global__ void fill_kernel(const int* __restrict__ srcArr,
                            const int* __restrict__ dstArr,
                            int* __restrict__ cursor, int* __restrict__ col)
{
    for (int e = blockIdx.x * blockDim.x + threadIdx.x; e < EE;
         e += gridDim.x * blockDim.x) {
        const int d = dstArr[e];
        const int pos = atomicAdd(&cursor[d], 1);
        col[pos] = srcArr[e];
    }
}

// ---------------------------------------------------------------------------
// Mean aggregation: one wave per node; lane holds float2 (128 cols / 64 lanes)
// ---------------------------------------------------------------------------
__global__ __launch_bounds__(256) void agg_kernel(
    const float* __restrict__ F, const int* __restrict__ row_ptr,
    const int* __restrict__ col, float* __restrict__ Mout)
{
    const int lane = threadIdx.x & 63;
    const int wave = blockIdx.x * (blockDim.x >> 6) + (threadIdx.x >> 6);
    const int nwaves = gridDim.x * (blockDim.x >> 6);

    for (int n = wave; n < NN; n += nwaves) {
        const int b = row_ptr[n];
        const int e = row_ptr[n + 1];
        const int deg = e - b;
        float accx = 0.0f, accy = 0.0f;
        int j = b;
        while (j < e) {
            const int m = (e - j < 64) ? (e - j) : 64;
            const int idx = (lane < m) ? col[j + lane] : 0;
            #pragma unroll 4
            for (int u = 0; u < m; u++) {
                const int s = __shfl(idx, u);
                const float2 v = *(const float2*)(F + (size_t)s * HIDC + lane * 2);
                accx += v.x; accy += v.y;
            }
            j += m;
        }
        const float inv = 1.0f / (float)(deg > 1 ? deg : 1);
        float2 r; r.x = accx * inv; r.y = accy * inv;
        *(float2*)(Mout + (size_t)n * HIDC + lane * 2) = r;
    }
}

// ---------------------------------------------------------------------------
extern "C" void kernel_launch(void* const* d_in, const int* in_sizes, int n_in,
                              void* d_out, int out_size, void* d_ws, size_t ws_size,
                              hipStream_t stream)
{
    const float* x     = (const float*)d_in[0];
    const int*   ei    = (const int*)  d_in[1];
    const float* W_in  = (const float*)d_in[2];
    const float* b_in  = (const float*)d_in[3];
    const float* g1    = (const float*)d_in[4];
    const float* be1   = (const float*)d_in[5];
    const float* W_hid = (const float*)d_in[6];
    const float* b_hid = (const float*)d_in[7];
    const float* g2    = (const float*)d_in[8];
    const float* be2   = (const float*)d_in[9];
    const float* Wl1   = (const float*)d_in[10];
    const float* bl1   = (const float*)d_in[11];
    const float* Wr1   = (const float*)d_in[12];
    const float* g3    = (const float*)d_in[13];
    const float* be3   = (const float*)d_in[14];
    const float* Wl2   = (const float*)d_in[15];
    const float* bl2   = (const float*)d_in[16];
    const float* Wr2   = (const float*)d_in[17];
    const float* g4    = (const float*)d_in[18];
    const float* be4   = (const float*)d_in[19];

    const int* srcArr = ei;        // edge_index[0]
    const int* dstArr = ei + EE;   // edge_index[1]

    char* ws = (char*)d_ws;
    float* bufA   = (float*)ws; ws += (size_t)NN * HIDC * sizeof(float);
    float* bufB   = (float*)ws; ws += (size_t)NN * HIDC * sizeof(float);
    float* stats  = (float*)ws; ws += 4 * 256 * sizeof(float);
    int*   deg    = (int*)ws;   ws += (size_t)NN * sizeof(int);
    int*   rowp   = (int*)ws;   ws += (size_t)(NN + 1) * sizeof(int);
    int*   cursor = (int*)ws;   ws += (size_t)NN * sizeof(int);
    int*   colIdx = (int*)ws;   ws += (size_t)EE * sizeof(int);

    float* out0 = (float*)d_out;             // feat  [NN*HID]
    float* out1 = out0 + (size_t)NN * HIDC;  // out   [NN*HID]

    // zero stats (4 stages) + deg — contiguous region, one memset
    hipMemsetAsync(stats, 0, 4 * 256 * sizeof(float) + (size_t)NN * sizeof(int), stream);

    // CSR build (independent of feature pipeline)
    hist_kernel<<<1024, 256, 0, stream>>>(dstArr, deg);
    scan_kernel<<<1, 256, 0, stream>>>(deg, rowp, cursor);
    fill_kernel<<<1024, 256, 0, stream>>>(srcArr, dstArr, cursor, colIdx);

    const int gemmGrid = (NN + 63) / 64;   // 782

    // stage 1: input linear + BN + relu  -> F1 (bufA, in place)
    gemm_kernel<<<gemmGrid, 256, 0, stream>>>(x, W_in, IN_DIMC, nullptr, nullptr, 0,
                                              b_in, bufA, NN);
    colstats_kernel<<<512, 256, 0, stream>>>(bufA, stats + 0, NN);
    bn_apply_kernel<<<1024, 256, 0, stream>>>(bufA, bufA, stats + 0, g1, be1, 1, NN);

    // stage 2: hidden linear + BN + relu -> feat (out0)
    gemm_kernel<<<gemmGrid, 256, 0, stream>>>(bufA, W_hid, HIDC, nullptr, nullptr, 0,
                                              b_hid, bufB, NN);
    colstats_kernel<<<512, 256, 0, stream>>>(bufB, stats + 256, NN);
    bn_apply_kernel<<<1024, 256, 0, stream>>>(bufB, out0, stats + 256, g2, be2, 1, NN);

    // stage 3: SAGE1 + BN -> O1 (bufA, in place)
    agg_kernel<<<4096, 256, 0, stream>>>(out0, rowp, colIdx, bufB);
    gemm_kernel<<<gemmGrid, 256, 0, stream>>>(bufB, Wl1, HIDC, out0, Wr1, HIDC,
                                              bl1, bufA, NN);
    colstats_kernel<<<512, 256, 0, stream>>>(bufA, stats + 512, NN);
    bn_apply_kernel<<<1024, 256, 0, stream>>>(bufA, bufA, stats + 512, g3, be3, 0, NN);

    // stage 4: SAGE2 + BN -> out (out1)
    agg_kernel<<<4096, 256, 0, stream>>>(bufA, rowp, colIdx, bufB);
    gemm_kernel<<<gemmGrid, 256, 0, stream>>>(bufB, Wl2, HIDC, bufA, Wr2, HIDC,
                                              bl2, out1, NN);
    colstats_kernel<<<512, 256, 0, stream>>>(out1, stats + 768, NN);
    bn_apply_kernel<<<1024, 256, 0, stream>>>(out1, out1, stats + 768, g4, be4, 0, NN);
}